// Round 1
// baseline (110.306 us; speedup 1.0000x reference)
//
#include <hip/hip_runtime.h>

// HMM posterior: out[b,t,s] = log_softmax_s(alphahat[t]+betahat[t]) — batch-independent
// (per-(b,t) scalar emission terms cancel in the state-axis softmax; observations unused).
// Linear space with max-rescale (scale cancels): p_t = p0 @ E^t, q_t = E^(T-1-t) @ 1, E=exp(A).
//
// K1 hmm_powers: M[k]=norm(E^(2^k)) + transposes via SPLIT-BF16 MFMA squarings
//                (X ~ hi+lo bf16; D = Ah*Bh + Ah*Bl + Al*Bh; rel err ~1e-5/squaring).
// K2 hmm_sg:     per-t binary-decomposition matvecs (L2-hot M/Mt) -> log-softmax row
//                -> write ONE 256-B sg row to workspace (compute only, no broadcast).
// K3 hmm_bcast:  pure broadcast of the 256-KB sg table to all 256 batches with
//                CONTIGUOUS 32-KB chunks per block (the old fused kernel scattered
//                256-B segments at 64-KB stride -> DRAM row-activate bound ~1.6 TB/s).

#define TT 1024
#define NK 10
#define PS 72   // bf16 plane stride in ushorts (144 B rows: 16B-aligned, 2-way banks = free)

typedef short  bf16x8 __attribute__((ext_vector_type(8)));
typedef float  f32x4  __attribute__((ext_vector_type(4)));

__device__ __forceinline__ unsigned short f2bf(float x) {
    unsigned u = __float_as_uint(x);
    unsigned r = u + 0x7fffu + ((u >> 16) & 1u);   // RNE; inputs finite
    return (unsigned short)(r >> 16);
}
__device__ __forceinline__ float bf2f(unsigned short h) {
    return __uint_as_float(((unsigned)h) << 16);
}

__global__ __launch_bounds__(256) void hmm_powers(const float* __restrict__ logA,
                                                  float* __restrict__ M,
                                                  float* __restrict__ Mt) {
    __shared__ unsigned short Ah[64 * PS], Al[64 * PS];   // row-major hi/lo planes
    __shared__ unsigned short Th[64 * PS], Tl[64 * PS];   // transposed hi/lo planes
    __shared__ float red4[4];
    const int tid  = threadIdx.x;
    const int wid  = tid >> 6;
    const int lane = tid & 63;

    // ---- E0 = exp(logA), normalized by max entry; emit fp32 M[0]/Mt[0] + bf16 planes.
    {
        const int row = tid >> 2;
        const int c0  = (tid & 3) * 16;
        float v[16];
        float lmax = 0.f;
        #pragma unroll
        for (int jj = 0; jj < 4; ++jj) {
            float4 x = ((const float4*)logA)[row * 16 + (tid & 3) * 4 + jj];
            float e0 = __expf(x.x), e1 = __expf(x.y), e2 = __expf(x.z), e3 = __expf(x.w);
            v[4 * jj + 0] = e0; v[4 * jj + 1] = e1; v[4 * jj + 2] = e2; v[4 * jj + 3] = e3;
            lmax = fmaxf(lmax, fmaxf(fmaxf(e0, e1), fmaxf(e2, e3)));
        }
        #pragma unroll
        for (int off = 32; off > 0; off >>= 1)
            lmax = fmaxf(lmax, __shfl_xor(lmax, off, 64));
        if (lane == 0) red4[wid] = lmax;
        __syncthreads();
        const float sc = 1.f / fmaxf(fmaxf(red4[0], red4[1]), fmaxf(red4[2], red4[3]));
        #pragma unroll
        for (int j = 0; j < 16; ++j) {
            float val = v[j] * sc;
            unsigned short hi = f2bf(val);
            unsigned short lo = f2bf(val - bf2f(hi));
            int cc = c0 + j;
            Ah[row * PS + cc] = hi;  Al[row * PS + cc] = lo;
            Th[cc * PS + row] = hi;  Tl[cc * PS + row] = lo;
            M [row * 64 + cc] = val;
            Mt[cc * 64 + row] = val;
        }
    }

    const int quad = (lane >> 4);
    const int l15  = lane & 15;

    // ---- 9 serial squarings, each: 24 MFMA/wave + hi/lo plane rewrite.
    for (int k = 1; k < NK; ++k) {
        __syncthreads();                       // planes ready
        f32x4 acc[4];
        #pragma unroll
        for (int c = 0; c < 4; ++c) acc[c] = (f32x4){0.f, 0.f, 0.f, 0.f};
        #pragma unroll
        for (int kk = 0; kk < 2; ++kk) {
            const int ao = (16 * wid + l15) * PS + 32 * kk + quad * 8;
            bf16x8 ah = *(const bf16x8*)&Ah[ao];
            bf16x8 al = *(const bf16x8*)&Al[ao];
            #pragma unroll
            for (int c = 0; c < 4; ++c) {
                const int bo = (16 * c + l15) * PS + 32 * kk + quad * 8;
                bf16x8 bh = *(const bf16x8*)&Th[bo];
                bf16x8 bl = *(const bf16x8*)&Tl[bo];
                acc[c] = __builtin_amdgcn_mfma_f32_16x16x32_bf16(ah, bh, acc[c], 0, 0, 0);
                acc[c] = __builtin_amdgcn_mfma_f32_16x16x32_bf16(ah, bl, acc[c], 0, 0, 0);
                acc[c] = __builtin_amdgcn_mfma_f32_16x16x32_bf16(al, bh, acc[c], 0, 0, 0);
            }
        }
        float m = 0.f;
        #pragma unroll
        for (int c = 0; c < 4; ++c)
            #pragma unroll
            for (int r = 0; r < 4; ++r) m = fmaxf(m, acc[c][r]);
        #pragma unroll
        for (int off = 32; off > 0; off >>= 1)
            m = fmaxf(m, __shfl_xor(m, off, 64));
        if (lane == 0) red4[wid] = m;
        __syncthreads();
        const float sc = 1.f / fmaxf(fmaxf(red4[0], red4[1]), fmaxf(red4[2], red4[3]));
        float* Mk  = M  + (k << 12);
        float* Mtk = Mt + (k << 12);
        #pragma unroll
        for (int c = 0; c < 4; ++c) {
            #pragma unroll
            for (int r = 0; r < 4; ++r) {
                float val = acc[c][r] * sc;
                const int rr = 16 * wid + quad * 4 + r;   // C/D: row = quad*4+reg (m89)
                const int cc = 16 * c   + l15;            //      col = lane&15
                Mk [rr * 64 + cc] = val;
                Mtk[cc * 64 + rr] = val;
                if (k < NK - 1) {
                    unsigned short hi = f2bf(val);
                    unsigned short lo = f2bf(val - bf2f(hi));
                    Ah[rr * PS + cc] = hi;  Al[rr * PS + cc] = lo;
                    Th[cc * PS + rr] = hi;  Tl[cc * PS + rr] = lo;
                }
            }
        }
    }
}

// 1024 blocks x 128 threads: wave 0 -> p_t, wave 1 -> q_t, log-softmax row,
// write ONE coalesced 256-B row sg[t][0..63] to workspace. Compute-latency bound
// (~6 serial L2-hot matvecs worst path); identical op order to the old fused kernel.
__global__ __launch_bounds__(128) void hmm_sg(const float* __restrict__ M,
                                              const float* __restrict__ Mt,
                                              const float* __restrict__ logInit,
                                              float* __restrict__ sg_ws) {
    const int t = blockIdx.x;
    __shared__ float sp[64];
    __shared__ float sq[64];
    const int lane = threadIdx.x & 63;
    const int w    = threadIdx.x >> 6;

    if (w == 0) {
        sp[lane] = __expf(logInit[lane]);
        const int e = t;
        for (int k = 0; k < NK; ++k) {
            if ((e >> k) & 1) {
                const float* Mk = M + (k << 12);
                float a0 = 0.f, a1 = 0.f, a2 = 0.f, a3 = 0.f;
                #pragma unroll
                for (int i = 0; i < 16; ++i) {
                    a0 = fmaf(sp[i],      Mk[( i       << 6) + lane], a0);
                    a1 = fmaf(sp[i + 16], Mk[((i + 16) << 6) + lane], a1);
                    a2 = fmaf(sp[i + 32], Mk[((i + 32) << 6) + lane], a2);
                    a3 = fmaf(sp[i + 48], Mk[((i + 48) << 6) + lane], a3);
                }
                float acc = (a0 + a1) + (a2 + a3);
                float mx = acc;
                #pragma unroll
                for (int off = 32; off > 0; off >>= 1)
                    mx = fmaxf(mx, __shfl_xor(mx, off, 64));
                sp[lane] = acc * (1.f / mx);
            }
        }
    } else {
        sq[lane] = 1.f;
        const int e = (TT - 1) - t;
        for (int k = 0; k < NK; ++k) {
            if ((e >> k) & 1) {
                const float* Mk = Mt + (k << 12);
                float a0 = 0.f, a1 = 0.f, a2 = 0.f, a3 = 0.f;
                #pragma unroll
                for (int i = 0; i < 16; ++i) {
                    a0 = fmaf(sq[i],      Mk[( i       << 6) + lane], a0);
                    a1 = fmaf(sq[i + 16], Mk[((i + 16) << 6) + lane], a1);
                    a2 = fmaf(sq[i + 32], Mk[((i + 32) << 6) + lane], a2);
                    a3 = fmaf(sq[i + 48], Mk[((i + 48) << 6) + lane], a3);
                }
                float acc = (a0 + a1) + (a2 + a3);
                float mx = acc;
                #pragma unroll
                for (int off = 32; off > 0; off >>= 1)
                    mx = fmaxf(mx, __shfl_xor(mx, off, 64));
                sq[lane] = acc * (1.f / mx);
            }
        }
    }
    __syncthreads();

    if (w == 0) {
        float gv = __logf(sp[lane]) + __logf(sq[lane]);
        float mx = gv;
        #pragma unroll
        for (int off = 32; off > 0; off >>= 1)
            mx = fmaxf(mx, __shfl_xor(mx, off, 64));
        float ex = __expf(gv - mx);
        float sm = ex;
        #pragma unroll
        for (int off = 32; off > 0; off >>= 1)
            sm += __shfl_xor(sm, off, 64);
        sg_ws[(t << 6) + lane] = gv - mx - __logf(sm);
    }
}

// Pure broadcast: out[b][t][s] = sg[t][s]. 2048 blocks x 256 threads;
// block (b = bid>>3, q = bid&7) streams a CONTIGUOUS 32-KB chunk of out[b]
// (reads 32 KB of the L3-resident 256-KB sg table, fully coalesced float4).
// 8 blocks/CU x 4 waves = 32 waves/CU -> write-roofline store stream.
__global__ __launch_bounds__(256) void hmm_bcast(const float* __restrict__ sg_ws,
                                                 float* __restrict__ out) {
    const int b = blockIdx.x >> 3;
    const int q = blockIdx.x & 7;
    const float4* s4 = (const float4*)sg_ws;
    float4*       o4 = (float4*)out;
    const int tid  = threadIdx.x;
    const int base = (q << 11) + tid;              // float4 units; 2048 f4 per chunk
    const size_t ob = (size_t)b * 16384;           // out[b] start, float4 units
    #pragma unroll
    for (int it = 0; it < 8; ++it) {
        int idx = base + (it << 8);
        o4[ob + idx] = s4[idx];
    }
}

extern "C" void kernel_launch(void* const* d_in, const int* in_sizes, int n_in,
                              void* d_out, int out_size, void* d_ws, size_t ws_size,
                              hipStream_t stream) {
    // inputs: [0] observations (unused), [1] log_transition (64x64 f32),
    //         [2] log_initial (64 f32), [3] log_emission (unused)
    const float* logA    = (const float*)d_in[1];
    const float* logInit = (const float*)d_in[2];
    float* M  = (float*)d_ws;              // 10 * 4096 floats
    float* Mt = M  + NK * 4096;            // 10 * 4096 floats
    float* sg = Mt + NK * 4096;            // 1024 * 64 floats (256 KB)
    hmm_powers<<<1, 256, 0, stream>>>(logA, M, Mt);
    hmm_sg<<<TT, 128, 0, stream>>>(M, Mt, logInit, sg);
    hmm_bcast<<<2048, 256, 0, stream>>>(sg, (float*)d_out);
}